// Round 7
// baseline (429.317 us; speedup 1.0000x reference)
//
#include <hip/hip_runtime.h>

// LSTM B=4096, T=512, I=1, H=64, O=1 (fp32 in/out).
// Round 7: SKEWED dual-group software pipeline. 256 thr / 16 batches / block,
// grid=256 (1 block/CU). Two 8-batch groups offset by HALF A STEP:
//   half1: group0 trans/update/write (acc from prev half) || group1 read+MFMA
//   half2: group1 trans/update/write || group0 read+MFMA (for t+1)
// Each barrier interval mixes trans-VALU of one group with LDS+MFMA of the
// other IN-STREAM -> guaranteed latency overlap (r6's in-phase groups gave
// zero overlap; r2/r4/r6 all ~1800 cyc per 16 batch-steps = exposed chain).
// Single h buffer per group: reads & writes of a buffer are always separated
// by a barrier in this schedule.
// Per group (r4 busy-minimal structure): hi/lo of h packed into M (row 2q=hi,
// 2q+1=lo of batch q), 8 MFMA/wave-step, all 4 gates of a cell colocated in
// one lane's acc regs (2 cells/lane), zero shuffles.
// MFMA layouts (m89-verified): A[m=lane&15][k=(lane>>4)*8+i],
// B[k=(lane>>4)*8+i][n=lane&15], D[m=(lane>>4)*4+r][n=lane&15].

#define TT   512
#define HP   72            // f16 row stride (144 B): 16B-aligned, 2-way max
#define BUFE (16 * HP)     // one h buffer: 16 rows
#define SXP  17            // sh_x row stride (floats), odd -> spread banks

typedef _Float16 f16x8 __attribute__((ext_vector_type(8)));
typedef float    f32x4 __attribute__((ext_vector_type(4)));

#define MFMA16(a, b, c) __builtin_amdgcn_mfma_f32_16x16x32_f16((a), (b), (c), 0, 0, 0)

__device__ __forceinline__ float rcp_(float x) { return __builtin_amdgcn_rcpf(x); }
__device__ __forceinline__ float sigmoid_(float x) { return rcp_(1.0f + __expf(-x)); }
__device__ __forceinline__ float tanh_(float x) { return 1.0f - 2.0f * rcp_(1.0f + __expf(2.0f * x)); }

__device__ __forceinline__ f16x8 cvt8(const float4& u0, const float4& u1) {
    f16x8 r;
    r[0] = (_Float16)u0.x; r[1] = (_Float16)u0.y; r[2] = (_Float16)u0.z; r[3] = (_Float16)u0.w;
    r[4] = (_Float16)u1.x; r[5] = (_Float16)u1.y; r[6] = (_Float16)u1.z; r[7] = (_Float16)u1.w;
    return r;
}

__global__ __launch_bounds__(256, 1) void lstm_mfma(
    const float* __restrict__ x,      // [4096, 512]
    const float* __restrict__ w_ih,   // [256]
    const float* __restrict__ w_hh,   // [256, 64]
    const float* __restrict__ b_ih,   // [256]
    const float* __restrict__ b_hh,   // [256]
    const float* __restrict__ w_out,  // [64]
    const float* __restrict__ b_out,  // [1]
    float* __restrict__ out)          // [4096]
{
    __shared__ __align__(16) float    sh_x[TT * SXP];   // [t][m16], 34.8 KB
    __shared__ __align__(16) _Float16 hbuf[2][BUFE];    // [group][..], 4.6 KB

    const int tid = threadIdx.x;
    const int w   = tid >> 6;    // wave 0..3 (owns N-tiles {w, w+4, w+8, w+12})
    const int L   = tid & 63;
    const int l16 = L & 15;
    const int h0  = L >> 4;      // 0..3
    const int b0  = blockIdx.x * 16;
    const int j   = 16 * w + l16;  // hidden unit col owned by this lane

    // ---- stage x: sh_x[t*SXP + m] = x[b0+m][t], m=0..15 (float4 coalesced) ----
    {
        const int half = tid >> 7;       // 0..1
        const int l    = tid & 127;
        const int t0   = 4 * l;
        #pragma unroll
        for (int q8 = 0; q8 < 8; ++q8) {
            const int q = q8 + 8 * half;
            float4 v = *(const float4*)(x + (size_t)(b0 + q) * TT + t0);
            sh_x[(t0 + 0) * SXP + q] = v.x;
            sh_x[(t0 + 1) * SXP + q] = v.y;
            sh_x[(t0 + 2) * SXP + q] = v.z;
            sh_x[(t0 + 3) * SXP + q] = v.w;
        }
    }
    // ---- zero h buffers (h(0) = 0 for both groups) ----
    for (int i = tid; i < 2 * BUFE; i += 256) (&hbuf[0][0])[i] = (_Float16)0.0f;

    // ---- preload W_hh fragments (fp16-rounded once) ----
    f16x8 Bf[4][2];
    float wihv[4], biasv[4];
    #pragma unroll
    for (int s = 0; s < 4; ++s) {
        const int n = 64 * s + j;
        #pragma unroll
        for (int kt = 0; kt < 2; ++kt) {
            const float* p = w_hh + n * 64 + kt * 32 + h0 * 8;
            float4 u0 = *(const float4*)p;
            float4 u1 = *(const float4*)(p + 4);
            Bf[s][kt] = cvt8(u0, u1);
        }
        wihv[s]  = w_ih[n];
        biasv[s] = b_ih[n] + b_hh[n];
    }

    // lane's cells per group: batches q=2h0, 2h0+1; A-frag row l16; writes
    // rows 4h0..4h0+3 (hi/lo of both batches), col j.
    const int aoff = l16 * HP + h0 * 8;   // f16 units; +32 for K-chunk 1
    const int wr0  = (4 * h0) * HP + j;

    float cc[2][2] = {{0.0f, 0.0f}, {0.0f, 0.0f}};

    // trans/update/write for group g at time t, given pre-gate acc
    auto do_cells = [&](int g, int t, const f32x4* acc) {
        const float2 xv = *(const float2*)(sh_x + t * SXP + 8 * g + 2 * h0);
        _Float16* wbg = hbuf[g];
        // cell 0: batch 2h0 (gate = acc[0]+acc[1])
        {
            float gi = (acc[0][0] + acc[0][1]) + fmaf(xv.x, wihv[0], biasv[0]);
            float gf = (acc[1][0] + acc[1][1]) + fmaf(xv.x, wihv[1], biasv[1]);
            float gg = (acc[2][0] + acc[2][1]) + fmaf(xv.x, wihv[2], biasv[2]);
            float go = (acc[3][0] + acc[3][1]) + fmaf(xv.x, wihv[3], biasv[3]);
            float i_ = sigmoid_(gi), f_ = sigmoid_(gf);
            float g_ = tanh_(gg),   o_ = sigmoid_(go);
            cc[g][0] = fmaf(f_, cc[g][0], i_ * g_);
            float hv = o_ * tanh_(cc[g][0]);
            _Float16 hh = (_Float16)hv;
            wbg[wr0]      = hh;
            wbg[wr0 + HP] = (_Float16)(hv - (float)hh);
        }
        // cell 1: batch 2h0+1 (gate = acc[2]+acc[3])
        {
            float gi = (acc[0][2] + acc[0][3]) + fmaf(xv.y, wihv[0], biasv[0]);
            float gf = (acc[1][2] + acc[1][3]) + fmaf(xv.y, wihv[1], biasv[1]);
            float gg = (acc[2][2] + acc[2][3]) + fmaf(xv.y, wihv[2], biasv[2]);
            float go = (acc[3][2] + acc[3][3]) + fmaf(xv.y, wihv[3], biasv[3]);
            float i_ = sigmoid_(gi), f_ = sigmoid_(gf);
            float g_ = tanh_(gg),   o_ = sigmoid_(go);
            cc[g][1] = fmaf(f_, cc[g][1], i_ * g_);
            float hv = o_ * tanh_(cc[g][1]);
            _Float16 hh = (_Float16)hv;
            wbg[wr0 + 2 * HP] = hh;
            wbg[wr0 + 3 * HP] = (_Float16)(hv - (float)hh);
        }
    };

    const f32x4 z = {0.f, 0.f, 0.f, 0.f};
    f32x4 accA[4] = {z, z, z, z};   // group0 pre-gates for t=0 (h(0)=0 -> 0)
    f32x4 accB[4];

    __syncthreads();

    for (int t = 0; t < TT; ++t) {
        // ---- half 1: group0 activations(t) || group1 read+MFMA(t) ----
        {
            f16x8 a0 = *(const f16x8*)(hbuf[1] + aoff);        // h1(t)
            f16x8 a1 = *(const f16x8*)(hbuf[1] + aoff + 32);
            do_cells(0, t, accA);                              // writes h0(t+1)
            #pragma unroll
            for (int s = 0; s < 4; ++s)
                accB[s] = MFMA16(a1, Bf[s][1], MFMA16(a0, Bf[s][0], z));
        }
        __syncthreads();
        // ---- half 2: group1 activations(t) || group0 read+MFMA(t+1) ----
        {
            f16x8 a0 = *(const f16x8*)(hbuf[0] + aoff);        // h0(t+1)
            f16x8 a1 = *(const f16x8*)(hbuf[0] + aoff + 32);
            do_cells(1, t, accB);                              // writes h1(t+1)
            #pragma unroll
            for (int s = 0; s < 4; ++s)
                accA[s] = MFMA16(a1, Bf[s][1], MFMA16(a0, Bf[s][0], z));
        }
        __syncthreads();
    }

    // ---- epilogue: wave w reduces batches {w, w+4, w+8, w+12} ----
    const float wo = w_out[L];
    #pragma unroll
    for (int p = 0; p < 4; ++p) {
        const int m = w + 4 * p;          // block-local batch 0..15
        const int g = m >> 3, q = m & 7;
        float hvf = (float)hbuf[g][(2 * q) * HP + L]
                  + (float)hbuf[g][(2 * q + 1) * HP + L];
        float v = hvf * wo;
        #pragma unroll
        for (int off = 32; off; off >>= 1) v += __shfl_down(v, off);
        if (L == 0) out[b0 + m] = v + b_out[0];
    }
}

extern "C" void kernel_launch(void* const* d_in, const int* in_sizes, int n_in,
                              void* d_out, int out_size, void* d_ws, size_t ws_size,
                              hipStream_t stream) {
    const float* x     = (const float*)d_in[0];
    const float* w_ih  = (const float*)d_in[1];
    const float* w_hh  = (const float*)d_in[2];
    const float* b_ih  = (const float*)d_in[3];
    const float* b_hh  = (const float*)d_in[4];
    const float* w_out = (const float*)d_in[5];
    const float* b_out = (const float*)d_in[6];
    float* out = (float*)d_out;

    lstm_mfma<<<256, 256, 0, stream>>>(x, w_ih, w_hh, b_ih, b_hh,
                                       w_out, b_out, out);
}

// Round 8
// 375.097 us; speedup vs baseline: 1.1446x; 1.1446x over previous
//
#include <hip/hip_runtime.h>

// LSTM B=4096, T=512, I=1, H=64, O=1 (fp32 in/out).
// Round 8: TRANSPOSED MFMA  G^T = W * H^T   (A = static weights in VGPRs,
// B = fresh h from LDS). Block = 256 thr / 16 batches, grid=256 (1 block/CU).
//   M = 256 gate rows (16 tiles), N = 16 batches, K = 128 (hi plane units
//   0..63 at kk=0..63, lo plane at kk=64..127; A-frags identical for both
//   planes -> only 2 A-frag sets/tile).
// Wave w owns M-tiles {w, w+4, w+8, w+12} -> lane (h0,l16) receives ALL 4
// gate types of units 16w+4h0+r (r=0..3) for batch l16 in its 16 acc regs:
// in-lane cell update, zero shuffles, NO acc pair-sums. Lane then writes its
// 4 contiguous units' h as ONE ds_write_b64 per plane. 4 ds_read_b128
// B-frags/step. One barrier/step, ping-pong h buffers.
// MFMA layouts (m89-verified): A[m=lane&15][k=(lane>>4)*8+i],
// B[k=(lane>>4)*8+i][n=lane&15], D[m=(lane>>4)*4+r][n=lane&15].

#define TT   512
#define US   72            // unit stride (f16) per (plane,batch) row: 144 B
#define BUFE (32 * US)     // one buffer: 2 planes x 16 batches
#define SXP  17            // sh_x row stride (floats)

typedef _Float16 f16x8 __attribute__((ext_vector_type(8)));
typedef _Float16 f16x4 __attribute__((ext_vector_type(4)));
typedef float    f32x4 __attribute__((ext_vector_type(4)));

#define MFMA16(a, b, c) __builtin_amdgcn_mfma_f32_16x16x32_f16((a), (b), (c), 0, 0, 0)

__device__ __forceinline__ float rcp_(float x) { return __builtin_amdgcn_rcpf(x); }
__device__ __forceinline__ float sigmoid_(float x) { return rcp_(1.0f + __expf(-x)); }
__device__ __forceinline__ float tanh_(float x) { return 1.0f - 2.0f * rcp_(1.0f + __expf(2.0f * x)); }

__global__ __launch_bounds__(256, 1) void lstm_t(
    const float* __restrict__ x,      // [4096, 512]
    const float* __restrict__ w_ih,   // [256]
    const float* __restrict__ w_hh,   // [256, 64]
    const float* __restrict__ b_ih,   // [256]
    const float* __restrict__ b_hh,   // [256]
    const float* __restrict__ w_out,  // [64]
    const float* __restrict__ b_out,  // [1]
    float* __restrict__ out)          // [4096]
{
    __shared__ __align__(16) float    sh_x[TT * SXP];   // [t][batch], 34.8 KB
    __shared__ __align__(16) _Float16 hbuf[2][BUFE];    // ping-pong, 18 KB

    const int tid = threadIdx.x;
    const int w   = tid >> 6;    // wave 0..3: owns units 16w..16w+15 (all 4 gate types)
    const int L   = tid & 63;
    const int l16 = L & 15;      // batch (N col) in B/D; weight row in A
    const int h0  = L >> 4;      // 0..3
    const int b0  = blockIdx.x * 16;

    // ---- stage x: sh_x[t*SXP + m] = x[b0+m][t], m=0..15 (float4 coalesced) ----
    {
        const int half = tid >> 7;
        const int l    = tid & 127;
        const int t0   = 4 * l;
        #pragma unroll
        for (int q8 = 0; q8 < 8; ++q8) {
            const int q = q8 + 8 * half;
            float4 v = *(const float4*)(x + (size_t)(b0 + q) * TT + t0);
            sh_x[(t0 + 0) * SXP + q] = v.x;
            sh_x[(t0 + 1) * SXP + q] = v.y;
            sh_x[(t0 + 2) * SXP + q] = v.z;
            sh_x[(t0 + 3) * SXP + q] = v.w;
        }
    }
    // ---- zero both h buffers (h(0) = 0) ----
    for (int i = tid; i < 2 * BUFE; i += 256) (&hbuf[0][0])[i] = (_Float16)0.0f;

    // ---- static A-frags (W fp16-rounded once) + per-lane gate constants ----
    // tile p (gate type p): rows n = 64p + 16w + l16; A[l16][kk=32e+8h0+i]
    // -> unit 32e+8h0+i (plane-independent).
    f16x8 Af[4][2];
    float wihv[4][4], biasv[4][4];
    #pragma unroll
    for (int p = 0; p < 4; ++p) {
        const int nb = 64 * p + 16 * w;
        {
            const int n = nb + l16;
            #pragma unroll
            for (int e = 0; e < 2; ++e) {
                const float* src = w_hh + n * 64 + 32 * e + 8 * h0;
                f16x8 a;
                #pragma unroll
                for (int i = 0; i < 8; ++i) a[i] = (_Float16)src[i];
                Af[p][e] = a;
            }
        }
        #pragma unroll
        for (int r = 0; r < 4; ++r) {
            const int n = nb + 4 * h0 + r;      // gate row this lane RECEIVES
            wihv[p][r]  = w_ih[n];
            biasv[p][r] = b_ih[n] + b_hh[n];
        }
    }

    // B-frag read base: row (plane c>>1, batch l16), units 32(c&1)+8h0..+7
    const int rbase = l16 * US + 8 * h0;            // chunk0; +32 / +16*US / +16*US+32
    // h write base: hi plane row l16, units 16w+4h0..+3 (lo at +16*US)
    const int wbase = l16 * US + 16 * w + 4 * h0;

    float cc[4] = {0.0f, 0.0f, 0.0f, 0.0f};
    __syncthreads();

    for (int t = 0; t < TT; ++t) {
        const _Float16* rb = hbuf[t & 1];
        _Float16*       wb = hbuf[(t + 1) & 1];

        f16x8 B0 = *(const f16x8*)(rb + rbase);                 // hi units 0..31
        f16x8 B1 = *(const f16x8*)(rb + rbase + 32);            // hi units 32..63
        f16x8 B2 = *(const f16x8*)(rb + rbase + 16 * US);       // lo units 0..31
        f16x8 B3 = *(const f16x8*)(rb + rbase + 16 * US + 32);  // lo units 32..63

        const f32x4 z = {0.f, 0.f, 0.f, 0.f};
        f32x4 acc[4];
        #pragma unroll
        for (int p = 0; p < 4; ++p)
            acc[p] = MFMA16(Af[p][1], B3,
                     MFMA16(Af[p][0], B2,
                     MFMA16(Af[p][1], B1,
                     MFMA16(Af[p][0], B0, z))));

        const float xv = sh_x[t * SXP + l16];
        f16x4 hhi, hlo;
        #pragma unroll
        for (int r = 0; r < 4; ++r) {
            float gi = acc[0][r] + fmaf(xv, wihv[0][r], biasv[0][r]);
            float gf = acc[1][r] + fmaf(xv, wihv[1][r], biasv[1][r]);
            float gg = acc[2][r] + fmaf(xv, wihv[2][r], biasv[2][r]);
            float go = acc[3][r] + fmaf(xv, wihv[3][r], biasv[3][r]);
            float i_ = sigmoid_(gi), f_ = sigmoid_(gf);
            float g_ = tanh_(gg),   o_ = sigmoid_(go);
            cc[r] = fmaf(f_, cc[r], i_ * g_);
            float hv = o_ * tanh_(cc[r]);
            _Float16 hh = (_Float16)hv;
            hhi[r] = hh;
            hlo[r] = (_Float16)(hv - (float)hh);
        }
        *(f16x4*)(wb + wbase)           = hhi;   // hi plane, 4 units, b64
        *(f16x4*)(wb + wbase + 16 * US) = hlo;   // lo plane
        __syncthreads();
    }

    // ---- epilogue: final h in hbuf[0]; wave w reduces batches 4w..4w+3 ----
    const float wo = w_out[L];
    #pragma unroll
    for (int bq = 0; bq < 4; ++bq) {
        const int b = 4 * w + bq;
        float hv = (float)hbuf[0][b * US + L] + (float)hbuf[0][(16 + b) * US + L];
        float v = hv * wo;
        #pragma unroll
        for (int off = 32; off; off >>= 1) v += __shfl_down(v, off);
        if (L == 0) out[b0 + b] = v + b_out[0];
    }
}

extern "C" void kernel_launch(void* const* d_in, const int* in_sizes, int n_in,
                              void* d_out, int out_size, void* d_ws, size_t ws_size,
                              hipStream_t stream) {
    const float* x     = (const float*)d_in[0];
    const float* w_ih  = (const float*)d_in[1];
    const float* w_hh  = (const float*)d_in[2];
    const float* b_ih  = (const float*)d_in[3];
    const float* b_hh  = (const float*)d_in[4];
    const float* w_out = (const float*)d_in[5];
    const float* b_out = (const float*)d_in[6];
    float* out = (float*)d_out;

    lstm_t<<<256, 256, 0, stream>>>(x, w_ih, w_hh, b_ih, b_hh,
                                    w_out, b_out, out);
}

// Round 9
// 319.331 us; speedup vs baseline: 1.3444x; 1.1746x over previous
//
#include <hip/hip_runtime.h>

// LSTM B=4096, T=512, I=1, H=64, O=1 (fp32 in/out).
// Round 9 = r4 (best: 347us, busy-minimal) + two changes:
//  (1) PHASE-STAGGER: co-resident blocks start in lockstep and execute
//      identical-length steps -> they stall on their barriers simultaneously
//      for all 512 steps (r4 idle ~555 cyc/step despite 2 indep blocks/CU).
//      Odd blocks (by a parity that splits both plausible pairings {i,i+256}
//      and {2i,2i+1}) sleep ~768 cyc before the loop -> anti-phase, each
//      block's VALU burst fills the other's chain stall.
//  (2) x*w_ih + bias enters as the MFMA C operand (hi rows only), deleting
//      8 fma + 8 add per wave-step from the post-MFMA serial chain.
// Structure (r4): MB=8, grid=512 (2 blocks/CU). hi/lo of h packed into M:
// row 2q=hi, 2q+1=lo of batch q; 8 MFMA/wave-step; all 4 gates of a cell in
// one lane's acc regs (2 cells/lane); one barrier/step; ping-pong h buffers.
// MFMA layouts (m89-verified): A[m=lane&15][k=(lane>>4)*8+i],
// B[k=(lane>>4)*8+i][n=lane&15], D[m=(lane>>4)*4+r][n=lane&15].

#define TT   512
#define MB   8
#define HP   72            // f16 row stride (144 B): 16B-aligned, 2-way max
#define BUFE (16 * HP)     // one ping-pong buffer: 16 rows
#define SXP  10            // sh_x row stride (floats)

typedef _Float16 f16x8 __attribute__((ext_vector_type(8)));
typedef float    f32x4 __attribute__((ext_vector_type(4)));

#define MFMA16(a, b, c) __builtin_amdgcn_mfma_f32_16x16x32_f16((a), (b), (c), 0, 0, 0)

__device__ __forceinline__ float rcp_(float x) { return __builtin_amdgcn_rcpf(x); }
__device__ __forceinline__ float sigmoid_(float x) { return rcp_(1.0f + __expf(-x)); }
__device__ __forceinline__ float tanh_(float x) { return 1.0f - 2.0f * rcp_(1.0f + __expf(2.0f * x)); }

__device__ __forceinline__ f16x8 cvt8(const float4& u0, const float4& u1) {
    f16x8 r;
    r[0] = (_Float16)u0.x; r[1] = (_Float16)u0.y; r[2] = (_Float16)u0.z; r[3] = (_Float16)u0.w;
    r[4] = (_Float16)u1.x; r[5] = (_Float16)u1.y; r[6] = (_Float16)u1.z; r[7] = (_Float16)u1.w;
    return r;
}

__global__ __launch_bounds__(256, 2) void lstm_mfma(
    const float* __restrict__ x,      // [4096, 512]
    const float* __restrict__ w_ih,   // [256]
    const float* __restrict__ w_hh,   // [256, 64]
    const float* __restrict__ b_ih,   // [256]
    const float* __restrict__ b_hh,   // [256]
    const float* __restrict__ w_out,  // [64]
    const float* __restrict__ b_out,  // [1]
    float* __restrict__ out)          // [4096]
{
    __shared__ __align__(16) float    sh_x[TT * SXP];   // [t][m], 20 KB
    __shared__ __align__(16) _Float16 hbuf[2 * BUFE];   // 4.6 KB

    const int tid = threadIdx.x;
    const int w   = tid >> 6;    // wave 0..3 (owns N-tiles {w, w+4, w+8, w+12})
    const int L   = tid & 63;
    const int l16 = L & 15;
    const int h0  = L >> 4;      // 0..3
    const int b0  = blockIdx.x * MB;
    const int j   = 16 * w + l16;  // hidden unit col owned by this lane

    // ---- stage x: sh_x[t*SXP + m] = x[b0+m][t] (coalesced) ----
    {
        const int q = tid >> 5;   // batch 0..7
        const int l = tid & 31;
        const float* xr = x + (size_t)(b0 + q) * TT;
        #pragma unroll
        for (int i = 0; i < TT / 32; ++i)
            sh_x[(l + 32 * i) * SXP + q] = xr[l + 32 * i];
    }
    // ---- zero both h buffers ----
    for (int i = tid; i < 2 * BUFE; i += 256) hbuf[i] = (_Float16)0.0f;

    // ---- preload W_hh fragments (fp16-rounded once) ----
    f16x8 Bf[4][2];
    float wihv[4], biasv[4];
    #pragma unroll
    for (int s = 0; s < 4; ++s) {
        const int n = 64 * s + j;
        #pragma unroll
        for (int kt = 0; kt < 2; ++kt) {
            const float* p = w_hh + n * 64 + kt * 32 + h0 * 8;
            float4 u0 = *(const float4*)p;
            float4 u1 = *(const float4*)(p + 4);
            Bf[s][kt] = cvt8(u0, u1);
        }
        wihv[s]  = w_ih[n];
        biasv[s] = b_ih[n] + b_hh[n];
    }

    // lane's A row m=l16: batch l16>>1, plane l16&1 (even=hi, odd=lo)
    const int aoff = l16 * HP + h0 * 8;   // f16 units; +32 for K-chunk 1
    // lane's cells: batches q0=2h0, q0+1; writes rows 4h0..4h0+3, col j
    const int xoff = 2 * h0;
    const int wr   = 4 * h0 * HP + j;

    float cc0 = 0.0f, cc1 = 0.0f;
    __syncthreads();

    // ---- phase stagger: desync co-resident blocks by ~half a step ----
    if (((blockIdx.x >> 8) ^ blockIdx.x) & 1) {
        __builtin_amdgcn_s_sleep(12);   // ~768 cyc
    }

    auto step = [&](const _Float16* rb, _Float16* wb, int t) {
        // A fragments: one row, 2 K-chunks
        f16x8 a0 = *(const f16x8*)(rb + aoff);
        f16x8 a1 = *(const f16x8*)(rb + aoff + 32);
        const float2 xv = *(const float2*)(sh_x + t * SXP + xoff);

        // xg + bias enters as the MFMA C operand on hi rows (r=0: batch 2h0,
        // r=2: batch 2h0+1); lo rows start at 0.
        f32x4 acc[4];
        #pragma unroll
        for (int s = 0; s < 4; ++s) {
            f32x4 ci = {fmaf(xv.x, wihv[s], biasv[s]), 0.f,
                        fmaf(xv.y, wihv[s], biasv[s]), 0.f};
            acc[s] = MFMA16(a1, Bf[s][1], MFMA16(a0, Bf[s][0], ci));
        }

        // cell 0: batch 2h0 (gate = acc[0]+acc[1], xg/bias already inside)
        {
            float gi = acc[0][0] + acc[0][1];
            float gf = acc[1][0] + acc[1][1];
            float gg = acc[2][0] + acc[2][1];
            float go = acc[3][0] + acc[3][1];
            float i_ = sigmoid_(gi), f_ = sigmoid_(gf);
            float g_ = tanh_(gg),   o_ = sigmoid_(go);
            cc0 = fmaf(f_, cc0, i_ * g_);
            float hv = o_ * tanh_(cc0);
            _Float16 hh = (_Float16)hv;
            wb[wr]      = hh;                          // row 4h0   (hi)
            wb[wr + HP] = (_Float16)(hv - (float)hh);  // row 4h0+1 (lo)
        }
        // cell 1: batch 2h0+1 (gate = acc[2]+acc[3])
        {
            float gi = acc[0][2] + acc[0][3];
            float gf = acc[1][2] + acc[1][3];
            float gg = acc[2][2] + acc[2][3];
            float go = acc[3][2] + acc[3][3];
            float i_ = sigmoid_(gi), f_ = sigmoid_(gf);
            float g_ = tanh_(gg),   o_ = sigmoid_(go);
            cc1 = fmaf(f_, cc1, i_ * g_);
            float hv = o_ * tanh_(cc1);
            _Float16 hh = (_Float16)hv;
            wb[wr + 2 * HP] = hh;                          // row 4h0+2 (hi)
            wb[wr + 3 * HP] = (_Float16)(hv - (float)hh);  // row 4h0+3 (lo)
        }
        __syncthreads();
    };

    for (int t = 0; t < TT; t += 2) {
        step(hbuf,        hbuf + BUFE, t);      // read buf0, write buf1
        step(hbuf + BUFE, hbuf,        t + 1);  // read buf1, write buf0
    }

    // ---- epilogue: final h in buf0; wave w reduces batches 2w, 2w+1 ----
    const float wo = w_out[L];
    #pragma unroll
    for (int p = 0; p < 2; ++p) {
        const int q = 2 * w + p;
        float hvf = (float)hbuf[(2 * q) * HP + L] + (float)hbuf[(2 * q + 1) * HP + L];
        float v = hvf * wo;
        #pragma unroll
        for (int off = 32; off; off >>= 1) v += __shfl_down(v, off);
        if (L == 0) out[b0 + q] = v + b_out[0];
    }
}

extern "C" void kernel_launch(void* const* d_in, const int* in_sizes, int n_in,
                              void* d_out, int out_size, void* d_ws, size_t ws_size,
                              hipStream_t stream) {
    const float* x     = (const float*)d_in[0];
    const float* w_ih  = (const float*)d_in[1];
    const float* w_hh  = (const float*)d_in[2];
    const float* b_ih  = (const float*)d_in[3];
    const float* b_hh  = (const float*)d_in[4];
    const float* w_out = (const float*)d_in[5];
    const float* b_out = (const float*)d_in[6];
    float* out = (float*)d_out;

    lstm_mfma<<<4096 / MB, 256, 0, stream>>>(x, w_ih, w_hh, b_ih, b_hh,
                                             w_out, b_out, out);
}